// Round 1
// baseline (41322.311 us; speedup 1.0000x reference)
//
#include <hip/hip_runtime.h>
#include <hip/hip_bf16.h>
#include <math.h>

// Problem constants
#define BDIM 4096     // batch
#define TLEN 48       // seq len
#define FEAT 35
#define HID 1024
#define H4 4096       // 4*HID
#define KIH 96        // padded 2*FEAT (70 -> 96, zero pad)

// GEMM tiling
#define BM 128
#define BN 128
#define BK 32
#define LDT 34        // padded LDS row stride (floats): 8*34 % 32 != 0 -> <=2-way conflicts

// ---------------- workspace layout (floats) ----------------
#define BH ((size_t)BDIM * HID)                 // 4,194,304
#define OFF_H      ((size_t)0)
#define OFF_C      (BH)
#define OFF_HDEC   (2*BH)
#define OFF_INPUTS (3*BH)                       // BDIM*KIH = 393,216
#define OFF_WHH    (3*BH + (size_t)BDIM*KIH)    // H4*HID = 4,194,304
#define OFF_WIH    (OFF_WHH + (size_t)H4*HID)   // H4*KIH = 393,216
#define OFF_BIAS   (OFF_WIH + (size_t)H4*KIH)   // 4096
#define OFF_TDWT   (OFF_BIAS + H4)              // FEAT*HID = 35,840
#define OFF_LOSS   (OFF_TDWT + (size_t)FEAT*HID) // 128 floats: [2t]=num,[2t+1]=den, [96]=bce_num,[97]=bce_den

// ---------------- prep kernels ----------------
// Reorder W_hh rows: orig n = g*HID + j  ->  new n = (j>>5)*128 + g*32 + (j&31)
__global__ __launch_bounds__(256) void prep_whh(const float* __restrict__ W_hh, float* __restrict__ Whh_r) {
    int newn = blockIdx.x;
    int nbk = newn >> 7, rem = newn & 127, g = rem >> 5, jl = rem & 31;
    int orig = g * HID + nbk * 32 + jl;
    const float4* s = (const float4*)(W_hh + (size_t)orig * HID);
    float4* d = (float4*)(Whh_r + (size_t)newn * HID);
    d[threadIdx.x] = s[threadIdx.x];
}

__global__ __launch_bounds__(128) void prep_wih(const float* __restrict__ W_ih, float* __restrict__ Wih_r) {
    int newn = blockIdx.x;
    int nbk = newn >> 7, rem = newn & 127, g = rem >> 5, jl = rem & 31;
    int orig = g * HID + nbk * 32 + jl;
    int k = threadIdx.x;
    if (k < KIH) {
        Wih_r[(size_t)newn * KIH + k] = (k < 2 * FEAT) ? W_ih[(size_t)orig * (2 * FEAT) + k] : 0.f;
    }
}

__global__ __launch_bounds__(256) void prep_bias(const float* __restrict__ b_ih, const float* __restrict__ b_hh,
                                                 float* __restrict__ bias_r) {
    int newn = blockIdx.x * 256 + threadIdx.x;
    int nbk = newn >> 7, rem = newn & 127, g = rem >> 5, jl = rem & 31;
    int orig = g * HID + nbk * 32 + jl;
    bias_r[newn] = b_ih[orig] + b_hh[orig];
}

// Transpose td_W [HID][FEAT] -> td_Wt [FEAT][HID]
__global__ __launch_bounds__(256) void prep_tdwt(const float* __restrict__ td_W, float* __restrict__ td_Wt) {
    int idx = blockIdx.x * 256 + threadIdx.x;   // FEAT*HID = 35840 exactly covered by 140*256
    int f = idx / HID, j = idx % HID;
    td_Wt[(size_t)f * HID + j] = td_W[(size_t)j * FEAT + f];
}

// ---------------- step kernel A: decay + regression + imputation + x_loss partial ----------------
__global__ __launch_bounds__(256) void stepA(const float* __restrict__ values, const float* __restrict__ masks,
                                             const float* __restrict__ deltas, const float* __restrict__ td_Wt,
                                             const float* __restrict__ td_b, const float* __restrict__ reg_W,
                                             const float* __restrict__ reg_b, const float* __restrict__ h,
                                             float* __restrict__ h_dec, float* __restrict__ inputs,
                                             float* __restrict__ imput, float* __restrict__ lossbuf, int t) {
    int b = blockIdx.x;
    int tid = threadIdx.x;
    __shared__ float d_sh[FEAT], x_sh[FEAT], m_sh[FEAT];
    __shared__ float hdec_sh[HID];
    __shared__ float red[4][FEAT];
    __shared__ float nb_sh[FEAT];

    const size_t base = ((size_t)b * TLEN + t) * FEAT;
    if (tid < FEAT) {
        d_sh[tid] = deltas[base + tid];
        x_sh[tid] = values[base + tid];
        m_sh[tid] = masks[base + tid];
    }
    __syncthreads();

    // phase 1: gamma = exp(-relu(d @ td_W.T + td_b)); h_dec = h * gamma
    #pragma unroll
    for (int u = 0; u < 4; u++) {
        int j = tid + u * 256;
        float s = td_b[j];
        #pragma unroll
        for (int f = 0; f < FEAT; f++) s += d_sh[f] * td_Wt[(size_t)f * HID + j];
        float gamma = expf(-fmaxf(s, 0.f));
        float hv = h[(size_t)b * HID + j] * gamma;
        hdec_sh[j] = hv;
        h_dec[(size_t)b * HID + j] = hv;
    }
    __syncthreads();

    // phase 2: x_h = h_dec @ reg_W.T + reg_b   (each wave covers 256 k's, lanes 0..34 = features)
    {
        int w = tid >> 6, lane = tid & 63;
        if (lane < FEAT) {
            float partial = 0.f;
            const float4* rw4 = (const float4*)(reg_W + (size_t)lane * HID + w * 256);
            const float4* h4 = (const float4*)(hdec_sh + w * 256);
            #pragma unroll 8
            for (int i = 0; i < 64; i++) {
                float4 a = rw4[i];
                float4 hh = h4[i];
                partial += a.x * hh.x + a.y * hh.y + a.z * hh.z + a.w * hh.w;
            }
            red[w][lane] = partial;
        }
    }
    __syncthreads();

    // phase 3: x_c, imputations, inputs buffer, loss partials
    if (tid < FEAT) {
        float xh = red[0][tid] + red[1][tid] + red[2][tid] + red[3][tid] + reg_b[tid];
        float xv = x_sh[tid], mv = m_sh[tid];
        float xc = mv * xv + (1.f - mv) * xh;
        imput[base + tid] = xc;
        inputs[(size_t)b * KIH + tid] = xc;
        inputs[(size_t)b * KIH + FEAT + tid] = mv;
        nb_sh[tid] = fabsf(xv - xh) * mv;
    }
    if (tid >= 2 * FEAT && tid < KIH) inputs[(size_t)b * KIH + tid] = 0.f;
    __syncthreads();
    if (tid == 0) {
        float n = 0.f, d = 0.f;
        for (int f = 0; f < FEAT; f++) { n += nb_sh[f]; d += m_sh[f]; }
        atomicAdd(&lossbuf[2 * t], n);
        atomicAdd(&lossbuf[2 * t + 1], d);
    }
}

// ---------------- step kernel B: gates GEMM + fused LSTM cell ----------------
__device__ inline void load_tile(float* __restrict__ sm, const float* __restrict__ src, int ld, int tid) {
    int row = tid >> 1;              // 0..127
    int cbase = (tid & 1) * 16;      // 0 or 16
    const float4* s4 = (const float4*)(src + (size_t)row * ld + cbase);
    #pragma unroll
    for (int i = 0; i < 4; i++) {
        float4 v = s4[i];
        float2* d2 = (float2*)(sm + row * LDT + cbase + i * 4);
        d2[0] = make_float2(v.x, v.y);
        d2[1] = make_float2(v.z, v.w);
    }
}

__device__ inline void compute_tile(float acc[8][8], const float* __restrict__ As, const float* __restrict__ Bs,
                                    int tx, int ty) {
    #pragma unroll
    for (int k = 0; k < BK; k++) {
        float a[8], bb[8];
        #pragma unroll
        for (int r = 0; r < 8; r++) a[r] = As[(ty * 8 + r) * LDT + k];
        #pragma unroll
        for (int g = 0; g < 4; g++) {
            bb[2 * g]     = Bs[(g * 32 + 2 * tx) * LDT + k];
            bb[2 * g + 1] = Bs[(g * 32 + 2 * tx + 1) * LDT + k];
        }
        #pragma unroll
        for (int r = 0; r < 8; r++)
            #pragma unroll
            for (int cc = 0; cc < 8; cc++) acc[r][cc] += a[r] * bb[cc];
    }
}

__global__ __launch_bounds__(256) void stepB(const float* __restrict__ h_dec, const float* __restrict__ inputs,
                                             const float* __restrict__ Whh_r, const float* __restrict__ Wih_r,
                                             const float* __restrict__ bias_r, float* __restrict__ c,
                                             float* __restrict__ h) {
    __shared__ float As[BM * LDT];
    __shared__ float Bs[BN * LDT];
    int nb = blockIdx.x, mb = blockIdx.y;
    int tid = threadIdx.x;
    int tx = tid & 15, ty = tid >> 4;

    float acc[8][8];
    #pragma unroll
    for (int r = 0; r < 8; r++)
        #pragma unroll
        for (int cc = 0; cc < 8; cc++) acc[r][cc] = 0.f;

    // main K loop over h_dec (K=1024) with Whh_r
    for (int kt = 0; kt < HID / BK; kt++) {
        load_tile(As, h_dec + (size_t)(mb * BM) * HID + kt * BK, HID, tid);
        load_tile(Bs, Whh_r + (size_t)(nb * BN) * HID + kt * BK, HID, tid);
        __syncthreads();
        compute_tile(acc, As, Bs, tx, ty);
        __syncthreads();
    }
    // ih part: K=96 over inputs with Wih_r
    for (int kt = 0; kt < KIH / BK; kt++) {
        load_tile(As, inputs + (size_t)(mb * BM) * KIH + kt * BK, KIH, tid);
        load_tile(Bs, Wih_r + (size_t)(nb * BN) * KIH + kt * BK, KIH, tid);
        __syncthreads();
        compute_tile(acc, As, Bs, tx, ty);
        __syncthreads();
    }

    // fused LSTM epilogue: this block owns b in [mb*128, mb*128+128), j in [nb*32, nb*32+32)
    float bi[2], bf[2], bg[2], bo[2];
    #pragma unroll
    for (int l = 0; l < 2; l++) {
        int jl = 2 * tx + l;
        bi[l] = bias_r[nb * 128 + jl];
        bf[l] = bias_r[nb * 128 + 32 + jl];
        bg[l] = bias_r[nb * 128 + 64 + jl];
        bo[l] = bias_r[nb * 128 + 96 + jl];
    }
    #pragma unroll
    for (int r = 0; r < 8; r++) {
        int brow = mb * BM + ty * 8 + r;
        #pragma unroll
        for (int l = 0; l < 2; l++) {
            int jg = nb * 32 + 2 * tx + l;
            float iv = acc[r][0 + l] + bi[l];
            float fv = acc[r][2 + l] + bf[l];
            float gv = acc[r][4 + l] + bg[l];
            float ov = acc[r][6 + l] + bo[l];
            iv = 1.f / (1.f + expf(-iv));
            fv = 1.f / (1.f + expf(-fv));
            ov = 1.f / (1.f + expf(-ov));
            gv = tanhf(gv);
            size_t idx = (size_t)brow * HID + jg;
            float cold = c[idx];
            float cnew = fv * cold + iv * gv;
            float hnew = ov * tanhf(cnew);
            c[idx] = cnew;
            h[idx] = hnew;
        }
    }
}

// ---------------- final kernels ----------------
__global__ __launch_bounds__(256) void finalY(const float* __restrict__ h, const float* __restrict__ out_W,
                                              const float* __restrict__ out_b, const float* __restrict__ labels,
                                              const float* __restrict__ is_train, float* __restrict__ preds,
                                              float* __restrict__ lossbuf) {
    int wave = threadIdx.x >> 6, lane = threadIdx.x & 63;
    int b = blockIdx.x * 4 + wave;
    const float4* h4 = (const float4*)(h + (size_t)b * HID);
    const float4* w4 = (const float4*)out_W;
    float s = 0.f;
    #pragma unroll
    for (int i = 0; i < 4; i++) {
        float4 a = h4[lane + i * 64];
        float4 w = w4[lane + i * 64];
        s += a.x * w.x + a.y * w.y + a.z * w.z + a.w * w.w;
    }
    #pragma unroll
    for (int off = 32; off; off >>= 1) s += __shfl_down(s, off);
    if (lane == 0) {
        float y = s + out_b[0];
        preds[b] = 1.f / (1.f + expf(-y));
        float lab = labels[b], it = is_train[b];
        float mv = fmaxf(-y, 0.f);
        float bce = y - y * lab + mv + logf(expf(-mv) + expf(-y - mv));
        atomicAdd(&lossbuf[96], bce * it);
        atomicAdd(&lossbuf[97], it);
    }
}

__global__ void finalZ(const float* __restrict__ lossbuf, float* __restrict__ out0) {
    if (threadIdx.x == 0) {
        float xl = 0.f;
        for (int t = 0; t < TLEN; t++) xl += lossbuf[2 * t] / (lossbuf[2 * t + 1] + 1e-5f);
        float yl = lossbuf[96] / (lossbuf[97] + 1e-5f);
        out0[0] = 0.3f * xl + 1.0f * yl;
    }
}

// ---------------- launch ----------------
extern "C" void kernel_launch(void* const* d_in, const int* in_sizes, int n_in,
                              void* d_out, int out_size, void* d_ws, size_t ws_size,
                              hipStream_t stream) {
    const float* values   = (const float*)d_in[0];
    const float* masks    = (const float*)d_in[1];
    const float* deltas   = (const float*)d_in[2];
    const float* labels   = (const float*)d_in[3];
    const float* is_train = (const float*)d_in[4];
    const float* td_W     = (const float*)d_in[5];
    const float* td_b     = (const float*)d_in[6];
    const float* W_ih     = (const float*)d_in[7];
    const float* W_hh     = (const float*)d_in[8];
    const float* b_ih     = (const float*)d_in[9];
    const float* b_hh     = (const float*)d_in[10];
    const float* reg_W    = (const float*)d_in[11];
    const float* reg_b    = (const float*)d_in[12];
    const float* out_W    = (const float*)d_in[13];
    const float* out_b    = (const float*)d_in[14];

    float* out = (float*)d_out;
    float* ws  = (float*)d_ws;

    float* h       = ws + OFF_H;
    float* c       = ws + OFF_C;
    float* h_dec   = ws + OFF_HDEC;
    float* inputs  = ws + OFF_INPUTS;
    float* Whh_r   = ws + OFF_WHH;
    float* Wih_r   = ws + OFF_WIH;
    float* bias_r  = ws + OFF_BIAS;
    float* td_Wt   = ws + OFF_TDWT;
    float* lossbuf = ws + OFF_LOSS;

    // zero h, c (contiguous) and loss accumulators
    hipMemsetAsync(h, 0, 2 * BH * sizeof(float), stream);
    hipMemsetAsync(lossbuf, 0, 128 * sizeof(float), stream);

    prep_whh<<<H4, 256, 0, stream>>>(W_hh, Whh_r);
    prep_wih<<<H4, 128, 0, stream>>>(W_ih, Wih_r);
    prep_bias<<<H4 / 256, 256, 0, stream>>>(b_ih, b_hh, bias_r);
    prep_tdwt<<<(FEAT * HID) / 256, 256, 0, stream>>>(td_W, td_Wt);

    float* imput = out + 1 + BDIM;   // imputations region of d_out
    for (int t = 0; t < TLEN; t++) {
        stepA<<<BDIM, 256, 0, stream>>>(values, masks, deltas, td_Wt, td_b, reg_W, reg_b,
                                        h, h_dec, inputs, imput, lossbuf, t);
        stepB<<<dim3(H4 / BN, BDIM / BM), 256, 0, stream>>>(h_dec, inputs, Whh_r, Wih_r, bias_r, c, h);
    }
    finalY<<<BDIM / 4, 256, 0, stream>>>(h, out_W, out_b, labels, is_train, out + 1, lossbuf);
    finalZ<<<1, 64, 0, stream>>>(lossbuf, out);
}

// Round 2
// 9205.112 us; speedup vs baseline: 4.4891x; 4.4891x over previous
//
#include <hip/hip_runtime.h>
#include <math.h>

// Problem constants
#define BDIM 4096
#define TLEN 48
#define FEAT 35
#define HID 1024
#define H4 4096
#define KTOT 1152      // 1024 (hh) + 128 (ih, 70 real + 58 zero pad)
#define KIH2 128

#define BH ((size_t)BDIM * HID)

typedef unsigned short u16;
typedef __bf16 bf16x8 __attribute__((ext_vector_type(8)));
typedef float f32x4 __attribute__((ext_vector_type(4)));

__device__ __forceinline__ float b2f(u16 u) {
    union { float f; unsigned i; } v; v.i = ((unsigned)u) << 16; return v.f;
}
__device__ __forceinline__ u16 f2b(float f) {
    union { float f; unsigned i; } v; v.f = f;
    unsigned r = v.i + 0x7FFF + ((v.i >> 16) & 1);
    return (u16)(r >> 16);
}
__device__ __forceinline__ float sigf(float x) { return __builtin_amdgcn_rcpf(1.f + __expf(-x)); }
__device__ __forceinline__ float tanh_fast(float x) { return 1.f - 2.f * __builtin_amdgcn_rcpf(1.f + __expf(2.f * x)); }

// ---------------- prep kernels ----------------
// Combined bf16 weight matrix W[4096][1152], rows reordered:
// orig n = g*HID + j  ->  new n = (j>>5)*128 + g*32 + (j&31)
__global__ __launch_bounds__(256) void prep_w(const float* __restrict__ W_hh, const float* __restrict__ W_ih,
                                              u16* __restrict__ W) {
    int newn = blockIdx.x;
    int nbk = newn >> 7, rem = newn & 127, g = rem >> 5, jl = rem & 31;
    int orig = g * HID + nbk * 32 + jl;
    u16* dst = W + (size_t)newn * KTOT;
    const float* src = W_hh + (size_t)orig * HID;
    #pragma unroll
    for (int it = 0; it < 4; ++it) { int k = it * 256 + threadIdx.x; dst[k] = f2b(src[k]); }
    int k2 = threadIdx.x;
    if (k2 < KIH2) dst[HID + k2] = (k2 < 2 * FEAT) ? f2b(W_ih[(size_t)orig * (2 * FEAT) + k2]) : (u16)0;
}

__global__ __launch_bounds__(256) void prep_bias(const float* __restrict__ b_ih, const float* __restrict__ b_hh,
                                                 float* __restrict__ bias_r) {
    int newn = blockIdx.x * 256 + threadIdx.x;
    int nbk = newn >> 7, rem = newn & 127, g = rem >> 5, jl = rem & 31;
    int orig = g * HID + nbk * 32 + jl;
    bias_r[newn] = b_ih[orig] + b_hh[orig];
}

__global__ __launch_bounds__(256) void prep_tdwt(const float* __restrict__ td_W, float* __restrict__ td_Wt) {
    int idx = blockIdx.x * 256 + threadIdx.x;   // FEAT*HID = 35840 = 140*256
    int f = idx / HID, j = idx % HID;
    td_Wt[(size_t)f * HID + j] = td_W[(size_t)j * FEAT + f];
}

// ---------------- step kernel A: decay + regression + imputation + x_loss partial ----------------
// Writes X[b][0:1024] = bf16(h_dec), X[b][1024:1152] = bf16([x_c(35) | m(35) | zeros(58)])
__global__ __launch_bounds__(256) void stepA(const float* __restrict__ values, const float* __restrict__ masks,
                                             const float* __restrict__ deltas, const float* __restrict__ td_Wt,
                                             const float* __restrict__ td_b, const float* __restrict__ reg_W,
                                             const float* __restrict__ reg_b, const u16* __restrict__ h,
                                             u16* __restrict__ X, float* __restrict__ imput,
                                             float* __restrict__ lossbuf, int t) {
    int b = blockIdx.x;
    int tid = threadIdx.x;
    __shared__ float d_sh[FEAT], x_sh[FEAT], m_sh[FEAT];
    __shared__ float hdec_sh[HID];
    __shared__ float red[4][FEAT];
    __shared__ float nb_sh[FEAT];

    const size_t base = ((size_t)b * TLEN + t) * FEAT;
    if (tid < FEAT) {
        d_sh[tid] = deltas[base + tid];
        x_sh[tid] = values[base + tid];
        m_sh[tid] = masks[base + tid];
    }
    __syncthreads();

    u16* Xrow = X + (size_t)b * KTOT;

    // phase 1: gamma = exp(-relu(d @ td_W.T + td_b)); h_dec = h * gamma
    #pragma unroll
    for (int u = 0; u < 4; u++) {
        int j = tid + u * 256;
        float s = td_b[j];
        #pragma unroll
        for (int f = 0; f < FEAT; f++) s += d_sh[f] * td_Wt[(size_t)f * HID + j];
        float gamma = __expf(-fmaxf(s, 0.f));
        float hv = b2f(h[(size_t)b * HID + j]) * gamma;
        hdec_sh[j] = hv;
        Xrow[j] = f2b(hv);
    }
    __syncthreads();

    // phase 2: x_h = h_dec @ reg_W.T + reg_b (fp32)
    {
        int w = tid >> 6, lane = tid & 63;
        if (lane < FEAT) {
            float partial = 0.f;
            const float4* rw4 = (const float4*)(reg_W + (size_t)lane * HID + w * 256);
            const float4* h4 = (const float4*)(hdec_sh + w * 256);
            #pragma unroll 8
            for (int i = 0; i < 64; i++) {
                float4 a = rw4[i];
                float4 hh = h4[i];
                partial += a.x * hh.x + a.y * hh.y + a.z * hh.z + a.w * hh.w;
            }
            red[w][lane] = partial;
        }
    }
    __syncthreads();

    // phase 3: x_c, imputations, LSTM input region of X, loss partials
    if (tid < FEAT) {
        float xh = red[0][tid] + red[1][tid] + red[2][tid] + red[3][tid] + reg_b[tid];
        float xv = x_sh[tid], mv = m_sh[tid];
        float xc = mv * xv + (1.f - mv) * xh;
        imput[base + tid] = xc;
        Xrow[HID + tid] = f2b(xc);
        Xrow[HID + FEAT + tid] = f2b(mv);
        nb_sh[tid] = fabsf(xv - xh) * mv;
    }
    if (tid >= 2 * FEAT && tid < KIH2) Xrow[HID + tid] = 0;
    __syncthreads();
    if (tid == 0) {
        float n = 0.f, d = 0.f;
        for (int f = 0; f < FEAT; f++) { n += nb_sh[f]; d += m_sh[f]; }
        atomicAdd(&lossbuf[2 * t], n);
        atomicAdd(&lossbuf[2 * t + 1], d);
    }
}

// ---------------- step kernel B: bf16 MFMA gates GEMM + fused LSTM cell ----------------
// Block: 128(M=batch) x 128(N=gate cols), 4 waves; wave w owns M rows [w*32, w*32+32), all 128 N.
// LDS tiles As/Bs: [128 rows][64 bf16], rows unpadded (128B), 16B-chunk XOR swizzle:
//   LDS chunkpos (row*8 + c) holds global chunk (c ^ (row&7)) of that row.
__global__ __launch_bounds__(256) void stepB(const u16* __restrict__ X, const u16* __restrict__ W,
                                             const float* __restrict__ bias_r, float* __restrict__ c,
                                             u16* __restrict__ h) {
    __shared__ u16 As[128 * 64];
    __shared__ u16 Bs[128 * 64];
    int nb = blockIdx.x, mb = blockIdx.y;
    int tid = threadIdx.x;
    int wave = tid >> 6, lane = tid & 63;
    int lrow = lane >> 3;            // 0..7 row within 8-row staging group
    int gchunk = (lane & 7) ^ lrow;  // swizzled global 16B-chunk to fetch
    int cl = lane & 15, quad = lane >> 4;

    f32x4 acc[2][8];
    #pragma unroll
    for (int mi = 0; mi < 2; ++mi)
        #pragma unroll
        for (int ni = 0; ni < 8; ++ni) acc[mi][ni] = (f32x4){0.f, 0.f, 0.f, 0.f};

    for (int kt = 0; kt < KTOT / 64; ++kt) {
        __syncthreads();   // previous tile's compute done before overwrite
        #pragma unroll
        for (int it = 0; it < 4; ++it) {
            int rl = wave * 32 + it * 8;  // wave-uniform group start row
            const u16* ga = X + (size_t)(mb * 128 + rl + lrow) * KTOT + kt * 64 + gchunk * 8;
            __builtin_amdgcn_global_load_lds((const __attribute__((address_space(1))) void*)ga,
                                             (__attribute__((address_space(3))) void*)(As + rl * 64),
                                             16, 0, 0);
            const u16* gb = W + (size_t)(nb * 128 + rl + lrow) * KTOT + kt * 64 + gchunk * 8;
            __builtin_amdgcn_global_load_lds((const __attribute__((address_space(1))) void*)gb,
                                             (__attribute__((address_space(3))) void*)(Bs + rl * 64),
                                             16, 0, 0);
        }
        __syncthreads();   // drain LDS-DMA before reads

        #pragma unroll
        for (int s = 0; s < 2; ++s) {
            int cs = (((4 * s + quad) ^ (cl & 7)) << 3);  // swizzled ushort offset within row
            bf16x8 a0 = *(const bf16x8*)(As + (wave * 32 + cl) * 64 + cs);
            bf16x8 a1 = *(const bf16x8*)(As + (wave * 32 + 16 + cl) * 64 + cs);
            bf16x8 bv[8];
            #pragma unroll
            for (int ni = 0; ni < 8; ++ni) bv[ni] = *(const bf16x8*)(Bs + (ni * 16 + cl) * 64 + cs);
            #pragma unroll
            for (int ni = 0; ni < 8; ++ni) {
                acc[0][ni] = __builtin_amdgcn_mfma_f32_16x16x32_bf16(a0, bv[ni], acc[0][ni], 0, 0, 0);
                acc[1][ni] = __builtin_amdgcn_mfma_f32_16x16x32_bf16(a1, bv[ni], acc[1][ni], 0, 0, 0);
            }
        }
    }

    // fused LSTM epilogue.
    // C-fragment: col = lane&15 (within 16-tile), row = quad*4 + reg.
    // N-tile ni covers local gate-cols [ni*16, ni*16+16); gate g of jl lives at ni = 2g + (jl>>4).
    #pragma unroll
    for (int mi = 0; mi < 2; ++mi) {
        #pragma unroll
        for (int r = 0; r < 4; ++r) {
            int b = mb * 128 + wave * 32 + mi * 16 + quad * 4 + r;
            #pragma unroll
            for (int jh = 0; jh < 2; ++jh) {
                int jl = jh * 16 + cl;
                int j = nb * 32 + jl;
                float iv = acc[mi][jh + 0][r] + bias_r[nb * 128 + jl];
                float fv = acc[mi][jh + 2][r] + bias_r[nb * 128 + 32 + jl];
                float gv = acc[mi][jh + 4][r] + bias_r[nb * 128 + 64 + jl];
                float ov = acc[mi][jh + 6][r] + bias_r[nb * 128 + 96 + jl];
                iv = sigf(iv); fv = sigf(fv); ov = sigf(ov); gv = tanh_fast(gv);
                size_t idx = (size_t)b * HID + j;
                float cn = fv * c[idx] + iv * gv;
                c[idx] = cn;
                h[idx] = f2b(ov * tanh_fast(cn));
            }
        }
    }
}

// ---------------- final kernels ----------------
__global__ __launch_bounds__(256) void finalY(const u16* __restrict__ h, const float* __restrict__ out_W,
                                              const float* __restrict__ out_b, const float* __restrict__ labels,
                                              const float* __restrict__ is_train, float* __restrict__ preds,
                                              float* __restrict__ lossbuf) {
    int wave = threadIdx.x >> 6, lane = threadIdx.x & 63;
    int b = blockIdx.x * 4 + wave;
    const u16* hp = h + (size_t)b * HID + lane * 16;
    const float* wp = out_W + lane * 16;
    float s = 0.f;
    #pragma unroll
    for (int i = 0; i < 16; i++) s += b2f(hp[i]) * wp[i];
    #pragma unroll
    for (int off = 32; off; off >>= 1) s += __shfl_down(s, off);
    if (lane == 0) {
        float y = s + out_b[0];
        preds[b] = 1.f / (1.f + expf(-y));
        float lab = labels[b], it = is_train[b];
        float mv = fmaxf(-y, 0.f);
        float bce = y - y * lab + mv + logf(expf(-mv) + expf(-y - mv));
        atomicAdd(&lossbuf[96], bce * it);
        atomicAdd(&lossbuf[97], it);
    }
}

__global__ void finalZ(const float* __restrict__ lossbuf, float* __restrict__ out0) {
    if (threadIdx.x == 0) {
        float xl = 0.f;
        for (int t = 0; t < TLEN; t++) xl += lossbuf[2 * t] / (lossbuf[2 * t + 1] + 1e-5f);
        float yl = lossbuf[96] / (lossbuf[97] + 1e-5f);
        out0[0] = 0.3f * xl + 1.0f * yl;
    }
}

// ---------------- launch ----------------
extern "C" void kernel_launch(void* const* d_in, const int* in_sizes, int n_in,
                              void* d_out, int out_size, void* d_ws, size_t ws_size,
                              hipStream_t stream) {
    const float* values   = (const float*)d_in[0];
    const float* masks    = (const float*)d_in[1];
    const float* deltas   = (const float*)d_in[2];
    const float* labels   = (const float*)d_in[3];
    const float* is_train = (const float*)d_in[4];
    const float* td_W     = (const float*)d_in[5];
    const float* td_b     = (const float*)d_in[6];
    const float* W_ih     = (const float*)d_in[7];
    const float* W_hh     = (const float*)d_in[8];
    const float* b_ih     = (const float*)d_in[9];
    const float* b_hh     = (const float*)d_in[10];
    const float* reg_W    = (const float*)d_in[11];
    const float* reg_b    = (const float*)d_in[12];
    const float* out_W    = (const float*)d_in[13];
    const float* out_b    = (const float*)d_in[14];

    float* out = (float*)d_out;
    float* ws_f = (float*)d_ws;

    // workspace layout: c fp32 [BH] | h bf16 [BH] | X bf16 [BDIM*KTOT] | W bf16 [H4*KTOT] | bias | td_Wt | loss
    float* c      = ws_f;
    u16*   h      = (u16*)(ws_f + BH);
    u16*   X      = (u16*)((char*)d_ws + BH * 6);
    u16*   W      = X + (size_t)BDIM * KTOT;
    float* bias_r = (float*)(W + (size_t)H4 * KTOT);
    float* td_Wt  = bias_r + H4;
    float* lossbuf = td_Wt + (size_t)FEAT * HID;

    hipMemsetAsync(ws_f, 0, BH * 6, stream);            // c (fp32) + h (bf16), contiguous
    hipMemsetAsync(lossbuf, 0, 128 * sizeof(float), stream);

    prep_w<<<H4, 256, 0, stream>>>(W_hh, W_ih, W);
    prep_bias<<<H4 / 256, 256, 0, stream>>>(b_ih, b_hh, bias_r);
    prep_tdwt<<<(FEAT * HID) / 256, 256, 0, stream>>>(td_W, td_Wt);

    float* imput = out + 1 + BDIM;
    for (int t = 0; t < TLEN; t++) {
        stepA<<<BDIM, 256, 0, stream>>>(values, masks, deltas, td_Wt, td_b, reg_W, reg_b,
                                        h, X, imput, lossbuf, t);
        stepB<<<dim3(H4 / 128, BDIM / 128), 256, 0, stream>>>(X, W, bias_r, c, h);
    }
    finalY<<<BDIM / 4, 256, 0, stream>>>(h, out_W, out_b, labels, is_train, out + 1, lossbuf);
    finalZ<<<1, 64, 0, stream>>>(lossbuf, out);
}

// Round 3
// 3898.301 us; speedup vs baseline: 10.6001x; 2.3613x over previous
//
#include <hip/hip_runtime.h>
#include <math.h>

// Problem constants
#define BDIM 4096
#define TLEN 48
#define FEAT 35
#define HID 1024
#define H4 4096
#define KTOT 1152      // 1024 (hh) + 128 (ih, 70 real + 58 zero pad)
#define KIH2 128

#define BH ((size_t)BDIM * HID)

typedef unsigned short u16;
typedef __bf16 bf16x8 __attribute__((ext_vector_type(8)));
typedef float f32x4 __attribute__((ext_vector_type(4)));

__device__ __forceinline__ float b2f(u16 u) {
    union { float f; unsigned i; } v; v.i = ((unsigned)u) << 16; return v.f;
}
__device__ __forceinline__ u16 f2b(float f) {
    union { float f; unsigned i; } v; v.f = f;
    unsigned r = v.i + 0x7FFF + ((v.i >> 16) & 1);
    return (u16)(r >> 16);
}
__device__ __forceinline__ float sigf(float x) { return __builtin_amdgcn_rcpf(1.f + __expf(-x)); }
__device__ __forceinline__ float tanh_fast(float x) { return 1.f - 2.f * __builtin_amdgcn_rcpf(1.f + __expf(2.f * x)); }

// ---------------- prep kernels ----------------
// Combined bf16 weight matrix W[4096][1152], rows reordered:
// orig n = g*HID + j  ->  new n = (j>>5)*128 + g*32 + (j&31)
__global__ __launch_bounds__(256) void prep_w(const float* __restrict__ W_hh, const float* __restrict__ W_ih,
                                              u16* __restrict__ W) {
    int newn = blockIdx.x;
    int nbk = newn >> 7, rem = newn & 127, g = rem >> 5, jl = rem & 31;
    int orig = g * HID + nbk * 32 + jl;
    u16* dst = W + (size_t)newn * KTOT;
    const float* src = W_hh + (size_t)orig * HID;
    #pragma unroll
    for (int it = 0; it < 4; ++it) { int k = it * 256 + threadIdx.x; dst[k] = f2b(src[k]); }
    int k2 = threadIdx.x;
    if (k2 < KIH2) dst[HID + k2] = (k2 < 2 * FEAT) ? f2b(W_ih[(size_t)orig * (2 * FEAT) + k2]) : (u16)0;
}

__global__ __launch_bounds__(256) void prep_bias(const float* __restrict__ b_ih, const float* __restrict__ b_hh,
                                                 float* __restrict__ bias_r) {
    int newn = blockIdx.x * 256 + threadIdx.x;
    int nbk = newn >> 7, rem = newn & 127, g = rem >> 5, jl = rem & 31;
    int orig = g * HID + nbk * 32 + jl;
    bias_r[newn] = b_ih[orig] + b_hh[orig];
}

// tdWtb[j][f] bf16, [1024][64], f>=35 zero.  td_W is [HID][FEAT] row-major already.
__global__ __launch_bounds__(256) void prep_tdwtb(const float* __restrict__ td_W, u16* __restrict__ tdWtb) {
    int idx = blockIdx.x * 256 + threadIdx.x;   // 1024*64 = 256*256
    int row = idx >> 6, f = idx & 63;
    tdWtb[idx] = (f < FEAT) ? f2b(td_W[(size_t)row * FEAT + f]) : (u16)0;
}

// regWb[f][k] bf16, [48][1024], f>=35 zero.  reg_W is [FEAT][HID] row-major.
__global__ __launch_bounds__(256) void prep_regwb(const float* __restrict__ reg_W, u16* __restrict__ regWb) {
    int idx = blockIdx.x * 256 + threadIdx.x;   // 48*1024 = 192*256
    int row = idx >> 10, col = idx & 1023;
    regWb[idx] = (row < FEAT) ? f2b(reg_W[(size_t)row * HID + col]) : (u16)0;
}

// ---------------- step kernel A: MFMA decay + regression + imputation + loss ----------------
// Block: 256 threads (4 waves), 16 batch rows. grid 256.
// Phase 1: gamma matmul via MFMA 16x16x32 (M=j-tile, N=16 batches, K=64 padded feats).
//          Each wave covers j-slice [wave*256, wave*256+256) (16 j-tiles).
// Phase 2: regression via MFMA (M=16 batches, N=48 feats, K split 256/wave), LDS reduce.
// Phase 3: x_c / imputations / X tail / loss epilogue.
__global__ __launch_bounds__(256) void stepA(const float* __restrict__ values, const float* __restrict__ masks,
                                             const float* __restrict__ deltas, const u16* __restrict__ tdWtb,
                                             const float* __restrict__ td_b, const u16* __restrict__ regWb,
                                             const float* __restrict__ reg_b, const u16* __restrict__ h,
                                             u16* __restrict__ X, float* __restrict__ imput,
                                             float* __restrict__ lossbuf, int t) {
    __shared__ u16 hdec_sh[16 * 1024];     // 32KB, 16B-chunk XOR swizzled per row
    __shared__ u16 d_bsh[16 * 72];         // bf16 d, padded K
    __shared__ float x_sh[16 * 35], m_sh[16 * 35];
    __shared__ float tdb_sh[1024];
    __shared__ float xhp[4][16][48];       // per-wave regression partials
    __shared__ float redbuf[8];

    int tid = threadIdx.x;
    int wave = tid >> 6, lane = tid & 63;
    int cl = lane & 15, quad = lane >> 4;
    int b0 = blockIdx.x * 16;

    // ---- stage td_b, d (bf16), x, m ----
    ((float4*)tdb_sh)[tid] = ((const float4*)td_b)[tid];
    for (int i = tid; i < 16 * 35; i += 256) {
        int b = i / 35, f = i - b * 35;
        size_t g = ((size_t)(b0 + b) * TLEN + t) * FEAT + f;
        d_bsh[b * 72 + f] = f2b(deltas[g]);
        x_sh[i] = values[g];
        m_sh[i] = masks[g];
    }
    for (int i = tid; i < 16 * 37; i += 256) {
        int b = i / 37, f = 35 + (i - b * 37);
        d_bsh[b * 72 + f] = 0;
    }
    __syncthreads();

    // ---- phase 1: decay ----
    // B-frag (n=batch=cl, k=feat): two K=32 steps
    bf16x8 db0 = *(const bf16x8*)(d_bsh + cl * 72 + quad * 8);
    bf16x8 db1 = *(const bf16x8*)(d_bsh + cl * 72 + 32 + quad * 8);
    const u16* hrow = h + (size_t)(b0 + cl) * HID;
    u16* Xrow = X + (size_t)(b0 + cl) * KTOT;

    #pragma unroll
    for (int jt = 0; jt < 16; ++jt) {
        int j0 = wave * 256 + jt * 16;
        const u16* ta = tdWtb + (size_t)(j0 + cl) * 64;
        bf16x8 a0 = *(const bf16x8*)(ta + quad * 8);
        bf16x8 a1 = *(const bf16x8*)(ta + 32 + quad * 8);
        f32x4 g4 = (f32x4){0.f, 0.f, 0.f, 0.f};
        g4 = __builtin_amdgcn_mfma_f32_16x16x32_bf16(a0, db0, g4, 0, 0, 0);
        g4 = __builtin_amdgcn_mfma_f32_16x16x32_bf16(a1, db1, g4, 0, 0, 0);
        // C: row (m) = quad*4+r = j within tile, col (n) = cl = batch
        int jq = j0 + quad * 4;
        float4 tb = *(const float4*)(tdb_sh + jq);
        ushort4 hv4 = *(const ushort4*)(hrow + jq);
        float s0 = g4[0] + tb.x, s1 = g4[1] + tb.y, s2 = g4[2] + tb.z, s3 = g4[3] + tb.w;
        float h0 = b2f(hv4.x) * __expf(-fmaxf(s0, 0.f));
        float h1 = b2f(hv4.y) * __expf(-fmaxf(s1, 0.f));
        float h2 = b2f(hv4.z) * __expf(-fmaxf(s2, 0.f));
        float h3 = b2f(hv4.w) * __expf(-fmaxf(s3, 0.f));
        ushort4 xo = make_ushort4(f2b(h0), f2b(h1), f2b(h2), f2b(h3));
        *(ushort4*)(Xrow + jq) = xo;
        // swizzled LDS write (8B = half of a 16B chunk)
        int c = jq >> 3;
        int c_sw = (c & ~7) | ((c & 7) ^ (cl & 7));
        *(ushort4*)(hdec_sh + cl * 1024 + c_sw * 8 + (quad & 1) * 4) = xo;
    }
    __syncthreads();

    // ---- phase 2: regression, K split across waves ----
    f32x4 acc[3];
    #pragma unroll
    for (int nt = 0; nt < 3; ++nt) acc[nt] = (f32x4){0.f, 0.f, 0.f, 0.f};
    int kbase = wave * 256;
    #pragma unroll
    for (int ks = 0; ks < 8; ++ks) {
        int k0 = kbase + ks * 32;
        int c = (k0 >> 3) + quad;
        int c_sw = (c & ~7) | ((c & 7) ^ (cl & 7));
        bf16x8 av = *(const bf16x8*)(hdec_sh + cl * 1024 + c_sw * 8);
        #pragma unroll
        for (int nt = 0; nt < 3; ++nt) {
            bf16x8 bv = *(const bf16x8*)(regWb + (size_t)(nt * 16 + cl) * 1024 + k0 + quad * 8);
            acc[nt] = __builtin_amdgcn_mfma_f32_16x16x32_bf16(av, bv, acc[nt], 0, 0, 0);
        }
    }
    #pragma unroll
    for (int nt = 0; nt < 3; ++nt)
        #pragma unroll
        for (int r = 0; r < 4; ++r)
            xhp[wave][quad * 4 + r][nt * 16 + cl] = acc[nt][r];
    __syncthreads();

    // ---- phase 3: epilogue ----
    float lossN = 0.f, lossD = 0.f;
    for (int i = tid; i < 16 * 35; i += 256) {
        int b = i / 35, f = i - b * 35;
        float xh = xhp[0][b][f] + xhp[1][b][f] + xhp[2][b][f] + xhp[3][b][f] + reg_b[f];
        float xv = x_sh[i], mv = m_sh[i];
        float xc = mv * xv + (1.f - mv) * xh;
        imput[((size_t)(b0 + b) * TLEN + t) * FEAT + f] = xc;
        u16* Xr = X + (size_t)(b0 + b) * KTOT;
        Xr[HID + f] = f2b(xc);
        Xr[HID + FEAT + f] = f2b(mv);
        lossN += fabsf(xv - xh) * mv;
        lossD += mv;
    }
    for (int i = tid; i < 16 * 58; i += 256) {
        int b = i / 58, k = i - b * 58;
        X[(size_t)(b0 + b) * KTOT + HID + 2 * FEAT + k] = 0;
    }
    #pragma unroll
    for (int off = 32; off; off >>= 1) {
        lossN += __shfl_down(lossN, off);
        lossD += __shfl_down(lossD, off);
    }
    if (lane == 0) { redbuf[wave] = lossN; redbuf[4 + wave] = lossD; }
    __syncthreads();
    if (tid == 0) {
        float n = redbuf[0] + redbuf[1] + redbuf[2] + redbuf[3];
        float d = redbuf[4] + redbuf[5] + redbuf[6] + redbuf[7];
        atomicAdd(&lossbuf[2 * t], n);
        atomicAdd(&lossbuf[2 * t + 1], d);
    }
}

// ---------------- step kernel B: bf16 MFMA gates GEMM + fused LSTM cell ----------------
__global__ __launch_bounds__(256) void stepB(const u16* __restrict__ X, const u16* __restrict__ W,
                                             const float* __restrict__ bias_r, float* __restrict__ c,
                                             u16* __restrict__ h) {
    __shared__ u16 As[128 * 64];
    __shared__ u16 Bs[128 * 64];
    int nb = blockIdx.x, mb = blockIdx.y;
    int tid = threadIdx.x;
    int wave = tid >> 6, lane = tid & 63;
    int lrow = lane >> 3;            // 0..7 row within 8-row staging group
    int gchunk = (lane & 7) ^ lrow;  // swizzled global 16B-chunk to fetch
    int cl = lane & 15, quad = lane >> 4;

    f32x4 acc[2][8];
    #pragma unroll
    for (int mi = 0; mi < 2; ++mi)
        #pragma unroll
        for (int ni = 0; ni < 8; ++ni) acc[mi][ni] = (f32x4){0.f, 0.f, 0.f, 0.f};

    for (int kt = 0; kt < KTOT / 64; ++kt) {
        __syncthreads();
        #pragma unroll
        for (int it = 0; it < 4; ++it) {
            int rl = wave * 32 + it * 8;
            const u16* ga = X + (size_t)(mb * 128 + rl + lrow) * KTOT + kt * 64 + gchunk * 8;
            __builtin_amdgcn_global_load_lds((const __attribute__((address_space(1))) void*)ga,
                                             (__attribute__((address_space(3))) void*)(As + rl * 64),
                                             16, 0, 0);
            const u16* gb = W + (size_t)(nb * 128 + rl + lrow) * KTOT + kt * 64 + gchunk * 8;
            __builtin_amdgcn_global_load_lds((const __attribute__((address_space(1))) void*)gb,
                                             (__attribute__((address_space(3))) void*)(Bs + rl * 64),
                                             16, 0, 0);
        }
        __syncthreads();

        #pragma unroll
        for (int s = 0; s < 2; ++s) {
            int cs = (((4 * s + quad) ^ (cl & 7)) << 3);
            bf16x8 a0 = *(const bf16x8*)(As + (wave * 32 + cl) * 64 + cs);
            bf16x8 a1 = *(const bf16x8*)(As + (wave * 32 + 16 + cl) * 64 + cs);
            bf16x8 bv[8];
            #pragma unroll
            for (int ni = 0; ni < 8; ++ni) bv[ni] = *(const bf16x8*)(Bs + (ni * 16 + cl) * 64 + cs);
            #pragma unroll
            for (int ni = 0; ni < 8; ++ni) {
                acc[0][ni] = __builtin_amdgcn_mfma_f32_16x16x32_bf16(a0, bv[ni], acc[0][ni], 0, 0, 0);
                acc[1][ni] = __builtin_amdgcn_mfma_f32_16x16x32_bf16(a1, bv[ni], acc[1][ni], 0, 0, 0);
            }
        }
    }

    #pragma unroll
    for (int mi = 0; mi < 2; ++mi) {
        #pragma unroll
        for (int r = 0; r < 4; ++r) {
            int b = mb * 128 + wave * 32 + mi * 16 + quad * 4 + r;
            #pragma unroll
            for (int jh = 0; jh < 2; ++jh) {
                int jl = jh * 16 + cl;
                int j = nb * 32 + jl;
                float iv = acc[mi][jh + 0][r] + bias_r[nb * 128 + jl];
                float fv = acc[mi][jh + 2][r] + bias_r[nb * 128 + 32 + jl];
                float gv = acc[mi][jh + 4][r] + bias_r[nb * 128 + 64 + jl];
                float ov = acc[mi][jh + 6][r] + bias_r[nb * 128 + 96 + jl];
                iv = sigf(iv); fv = sigf(fv); ov = sigf(ov); gv = tanh_fast(gv);
                size_t idx = (size_t)b * HID + j;
                float cn = fv * c[idx] + iv * gv;
                c[idx] = cn;
                h[idx] = f2b(ov * tanh_fast(cn));
            }
        }
    }
}

// ---------------- final kernels ----------------
__global__ __launch_bounds__(256) void finalY(const u16* __restrict__ h, const float* __restrict__ out_W,
                                              const float* __restrict__ out_b, const float* __restrict__ labels,
                                              const float* __restrict__ is_train, float* __restrict__ preds,
                                              float* __restrict__ lossbuf) {
    int wave = threadIdx.x >> 6, lane = threadIdx.x & 63;
    int b = blockIdx.x * 4 + wave;
    const u16* hp = h + (size_t)b * HID + lane * 16;
    const float* wp = out_W + lane * 16;
    float s = 0.f;
    #pragma unroll
    for (int i = 0; i < 16; i++) s += b2f(hp[i]) * wp[i];
    #pragma unroll
    for (int off = 32; off; off >>= 1) s += __shfl_down(s, off);
    if (lane == 0) {
        float y = s + out_b[0];
        preds[b] = 1.f / (1.f + expf(-y));
        float lab = labels[b], it = is_train[b];
        float mv = fmaxf(-y, 0.f);
        float bce = y - y * lab + mv + logf(expf(-mv) + expf(-y - mv));
        atomicAdd(&lossbuf[96], bce * it);
        atomicAdd(&lossbuf[97], it);
    }
}

__global__ void finalZ(const float* __restrict__ lossbuf, float* __restrict__ out0) {
    if (threadIdx.x == 0) {
        float xl = 0.f;
        for (int t = 0; t < TLEN; t++) xl += lossbuf[2 * t] / (lossbuf[2 * t + 1] + 1e-5f);
        float yl = lossbuf[96] / (lossbuf[97] + 1e-5f);
        out0[0] = 0.3f * xl + 1.0f * yl;
    }
}

// ---------------- launch ----------------
extern "C" void kernel_launch(void* const* d_in, const int* in_sizes, int n_in,
                              void* d_out, int out_size, void* d_ws, size_t ws_size,
                              hipStream_t stream) {
    const float* values   = (const float*)d_in[0];
    const float* masks    = (const float*)d_in[1];
    const float* deltas   = (const float*)d_in[2];
    const float* labels   = (const float*)d_in[3];
    const float* is_train = (const float*)d_in[4];
    const float* td_W     = (const float*)d_in[5];
    const float* td_b     = (const float*)d_in[6];
    const float* W_ih     = (const float*)d_in[7];
    const float* W_hh     = (const float*)d_in[8];
    const float* b_ih     = (const float*)d_in[9];
    const float* b_hh     = (const float*)d_in[10];
    const float* reg_W    = (const float*)d_in[11];
    const float* reg_b    = (const float*)d_in[12];
    const float* out_W    = (const float*)d_in[13];
    const float* out_b    = (const float*)d_in[14];

    float* out = (float*)d_out;
    float* ws_f = (float*)d_ws;

    // workspace: c f32[BH] | h bf16[BH] | X bf16[BDIM*KTOT] | W bf16[H4*KTOT] | bias f32[H4]
    //            | tdWtb bf16[1024*64] | regWb bf16[48*1024] | lossbuf
    float* c      = ws_f;
    u16*   h      = (u16*)(ws_f + BH);
    u16*   X      = (u16*)((char*)d_ws + BH * 6);
    u16*   W      = X + (size_t)BDIM * KTOT;
    float* bias_r = (float*)(W + (size_t)H4 * KTOT);
    u16*   tdWtb  = (u16*)(bias_r + H4);
    u16*   regWb  = tdWtb + 1024 * 64;
    float* lossbuf = (float*)(regWb + 48 * 1024);

    hipMemsetAsync(ws_f, 0, BH * 6, stream);            // c (fp32) + h (bf16)
    hipMemsetAsync(lossbuf, 0, 128 * sizeof(float), stream);

    prep_w<<<H4, 256, 0, stream>>>(W_hh, W_ih, W);
    prep_bias<<<H4 / 256, 256, 0, stream>>>(b_ih, b_hh, bias_r);
    prep_tdwtb<<<256, 256, 0, stream>>>(td_W, tdWtb);
    prep_regwb<<<192, 256, 0, stream>>>(reg_W, regWb);

    float* imput = out + 1 + BDIM;
    for (int t = 0; t < TLEN; t++) {
        stepA<<<BDIM / 16, 256, 0, stream>>>(values, masks, deltas, tdWtb, td_b, regWb, reg_b,
                                             h, X, imput, lossbuf, t);
        stepB<<<dim3(H4 / 128, BDIM / 128), 256, 0, stream>>>(X, W, bias_r, c, h);
    }
    finalY<<<BDIM / 4, 256, 0, stream>>>(h, out_W, out_b, labels, is_train, out + 1, lossbuf);
    finalZ<<<1, 64, 0, stream>>>(lossbuf, out);
}